// Round 3
// baseline (1785.587 us; speedup 1.0000x reference)
//
#include <hip/hip_runtime.h>
#include <hip/hip_bf16.h>
#include <math.h>

#define B_    32
#define T_    1024
#define D_    384
#define MAXF  4608
#define NTOK  (B_ * T_)          // 32768
#define TPAD  1026               // per-batch padded token rows (zero row each side)
#define NPROW (B_ * TPAD)        // 32832 padded rows
#define EPS_  1e-5f

typedef __bf16 bf16x8 __attribute__((ext_vector_type(8)));
typedef float  f32x4  __attribute__((ext_vector_type(4)));

// ---- fp32 <-> bf16 (RTNE) on raw bits ------------------------------------
__device__ __forceinline__ ushort f2bf(float f) {
    uint x = __float_as_uint(f);
    uint r = (x + 0x7FFFu + ((x >> 16) & 1u)) >> 16;
    return (ushort)r;
}
__device__ __forceinline__ float bf2f(ushort u) {
    return __uint_as_float(((uint)u) << 16);
}
__device__ __forceinline__ void split3(float v, ushort& a, ushort& b, ushort& c) {
    a = f2bf(v);        float r1 = v  - bf2f(a);
    b = f2bf(r1);       float r2 = r1 - bf2f(b);
    c = f2bf(r2);
}

__device__ __forceinline__ void gll16(const ushort* src, ushort* lds_dst) {
    __builtin_amdgcn_global_load_lds(
        (const __attribute__((address_space(1))) void*)src,
        (__attribute__((address_space(3))) void*)lds_dst, 16, 0, 0);
}

// ---------------------------------------------------------------------------
// prep kernel: fuses split_x (x -> 3 padded bf16 planes) and split_w for both
// conv weights (fp32 [3,384,384] -> 3 transposed bf16 planes [384 n][1152 kf]).
// ---------------------------------------------------------------------------
#define XBLKS ((NPROW + 3) / 4)      // 8208 blocks, 4 rows each
#define WBLKS ((384 * 576 + 255) / 256)  // 864 blocks per weight tensor

__global__ __launch_bounds__(256)
void prep_kernel(const float* __restrict__ x,
                 ushort* __restrict__ X0, ushort* __restrict__ X1, ushort* __restrict__ X2,
                 const float* __restrict__ w1,
                 ushort* __restrict__ W0, ushort* __restrict__ W1, ushort* __restrict__ W2,
                 const float* __restrict__ w2,
                 ushort* __restrict__ V0, ushort* __restrict__ V1, ushort* __restrict__ V2)
{
    int blk = blockIdx.x;
    if (blk < XBLKS) {
        const int row  = (int)((blk * 256 + threadIdx.x) >> 6);
        const int lane = threadIdx.x & 63;
        if (row >= NPROW) return;
        const int b = row / TPAD, tk = row % TPAD;

        uint* p0 = (uint*)X0 + (size_t)row * 192;
        uint* p1 = (uint*)X1 + (size_t)row * 192;
        uint* p2 = (uint*)X2 + (size_t)row * 192;

        if (tk == 0 || tk == TPAD - 1) {
            #pragma unroll
            for (int j = 0; j < 3; ++j) {
                p0[j * 64 + lane] = 0u; p1[j * 64 + lane] = 0u; p2[j * 64 + lane] = 0u;
            }
            return;
        }
        const float* src = x + ((size_t)b * T_ + (tk - 1)) * D_;
        #pragma unroll
        for (int j = 0; j < 3; ++j) {
            float2 t = *(const float2*)(src + j * 128 + lane * 2);
            ushort a0, b0, c0, a1, b1, c1;
            split3(t.x, a0, b0, c0);
            split3(t.y, a1, b1, c1);
            p0[j * 64 + lane] = (uint)a0 | ((uint)a1 << 16);
            p1[j * 64 + lane] = (uint)b0 | ((uint)b1 << 16);
            p2[j * 64 + lane] = (uint)c0 | ((uint)c1 << 16);
        }
        return;
    }
    blk -= XBLKS;
    const float* w;
    ushort *P0, *P1, *P2;
    if (blk < WBLKS) { w = w1; P0 = W0; P1 = W1; P2 = W2; }
    else { blk -= WBLKS; w = w2; P0 = V0; P1 = V1; P2 = V2; }

    const int p = blk * 256 + threadIdx.x;     // pair index
    if (p >= 384 * 576) return;
    const int n = p / 576, kp = p % 576;
    const int kf0 = kp * 2;
    float w0 = w[(size_t)kf0 * 384 + n];
    float w1v = w[(size_t)(kf0 + 1) * 384 + n];
    ushort a0, b0, c0, a1, b1, c1;
    split3(w0, a0, b0, c0);
    split3(w1v, a1, b1, c1);
    ((uint*)P0)[(size_t)n * 576 + kp] = (uint)a0 | ((uint)a1 << 16);
    ((uint*)P1)[(size_t)n * 576 + kp] = (uint)b0 | ((uint)b1 << 16);
    ((uint*)P2)[(size_t)n * 576 + kp] = (uint)c0 | ((uint)c1 << 16);
}

// ---------------------------------------------------------------------------
// ln_split: LN(conv1_out) -> 3 bf16 padded planes (conv2's A operand).
// ---------------------------------------------------------------------------
__global__ __launch_bounds__(256)
void ln_split_kernel(const float* __restrict__ in, const float* __restrict__ g,
                     const float* __restrict__ bta,
                     ushort* __restrict__ P0, ushort* __restrict__ P1, ushort* __restrict__ P2)
{
    const int row  = (int)((blockIdx.x * blockDim.x + threadIdx.x) >> 6);
    const int lane = threadIdx.x & 63;
    if (row >= NPROW) return;
    const int b = row / TPAD, tk = row % TPAD;

    uint* p0 = (uint*)P0 + (size_t)row * 192;
    uint* p1 = (uint*)P1 + (size_t)row * 192;
    uint* p2 = (uint*)P2 + (size_t)row * 192;

    if (tk == 0 || tk == TPAD - 1) {
        #pragma unroll
        for (int j = 0; j < 3; ++j) {
            p0[j * 64 + lane] = 0u; p1[j * 64 + lane] = 0u; p2[j * 64 + lane] = 0u;
        }
        return;
    }
    const float* src = in + ((size_t)b * T_ + (tk - 1)) * D_;

    float v[6];
    float s = 0.f;
    #pragma unroll
    for (int j = 0; j < 3; ++j) {
        float2 t = *(const float2*)(src + j * 128 + lane * 2);
        v[2 * j] = t.x; v[2 * j + 1] = t.y;
        s += t.x + t.y;
    }
    #pragma unroll
    for (int off = 32; off >= 1; off >>= 1) s += __shfl_xor(s, off);
    const float mean = s / 384.f;
    float q = 0.f;
    #pragma unroll
    for (int k = 0; k < 6; ++k) { float d = v[k] - mean; q += d * d; }
    #pragma unroll
    for (int off = 32; off >= 1; off >>= 1) q += __shfl_xor(q, off);
    const float rstd = 1.0f / sqrtf(q / 384.f + EPS_);

    #pragma unroll
    for (int j = 0; j < 3; ++j) {
        const int c = j * 128 + lane * 2;
        float o0 = (v[2 * j]     - mean) * rstd * g[c]     + bta[c];
        float o1 = (v[2 * j + 1] - mean) * rstd * g[c + 1] + bta[c + 1];
        ushort a0, b0, c0, a1, b1, c1;
        split3(o0, a0, b0, c0);
        split3(o1, a1, b1, c1);
        p0[j * 64 + lane] = (uint)a0 | ((uint)a1 << 16);
        p1[j * 64 + lane] = (uint)b0 | ((uint)b1 << 16);
        p2[j * 64 + lane] = (uint)c0 | ((uint)c1 << 16);
    }
}

// ---------------------------------------------------------------------------
// conv as bf16x6 MFMA GEMM, plane-shared staging.
// Per stage (tap t, k-chunk kc of 32): stage A0,A1,A2,B0,B1,B2 tiles
// (128 rows x 32 k each, 8 KB) into one 48 KB buffer (double-buffered),
// then run all 6 split combos (96 MFMA/wave) from LDS.
// One __syncthreads per stage; next-stage loads issued before compute.
// Tile 128x128, 4 waves (64x64 each), grid 768 XCD-swizzled.
// ---------------------------------------------------------------------------
__global__ __launch_bounds__(256, 1)
void conv_mfma_kernel(const ushort* __restrict__ A0, const ushort* __restrict__ A1,
                      const ushort* __restrict__ A2,
                      const ushort* __restrict__ B0, const ushort* __restrict__ B1,
                      const ushort* __restrict__ B2,
                      const float* __restrict__ bias, float* __restrict__ Y)
{
    __shared__ ushort smem[49152];   // 2 bufs x 6 tiles x 128x32 bf16 = 96 KB

    // --- XCD swizzle: 768 blocks, 96 per XCD; 3 col-blocks of a row share XCD
    const int bid = blockIdx.x;
    const int u   = (bid & 7) * 96 + (bid >> 3);
    const int rb  = u / 3, cb = u - 3 * rb;
    const int row0 = rb * 128;
    const int col0 = cb * 128;
    const int b    = row0 >> 10;
    const int tk0  = row0 & (T_ - 1);

    const int tid  = threadIdx.x;
    const int wid  = tid >> 6;
    const int lane = tid & 63;
    const int wr   = wid >> 1, wc = wid & 1;     // wave sub-tile (64x64)

    // --- staging lane constants: 1 KB wave-load = 16 rows x 64B; 4 chunks/row
    const int r0l  = lane >> 2;                  // sub-row 0..15
    const int cswl = (lane & 3) ^ (r0l & 3);     // source-side XOR chunk swizzle
    const size_t aRow0 = (size_t)(b * TPAD + tk0);

    // --- fragment-read constants
    const int lm = lane & 15, gk = lane >> 4;
    const int xorc  = ((gk ^ (lm & 3)) << 4);    // byte offset of swizzled chunk
    const int raddA = (wr * 64 + lm) * 64 + xorc;
    const int raddB = (wc * 64 + lm) * 64 + xorc;

    f32x4 acc[4][4];
    #pragma unroll
    for (int i = 0; i < 4; ++i)
        #pragma unroll
        for (int j = 0; j < 4; ++j) { f32x4 z = {0.f, 0.f, 0.f, 0.f}; acc[i][j] = z; }

    // stage (t, kc) into buffer bf (0/1): 12 wave-loads per wave
    auto STAGE = [&](int t, int kc, int bf) {
        const int koff = kc * 32 + cswl * 8;
        ushort* dst0 = smem + bf * 24576;
        #pragma unroll
        for (int i = 0; i < 12; ++i) {
            const int l   = wid * 12 + i;
            const int p   = l >> 3;               // 0..5: A0,A1,A2,B0,B1,B2
            const int sub = l & 7;                // 16-row group
            const int r   = sub * 16 + r0l;
            const ushort* src;
            if (p < 3) {
                const ushort* Ap = (p == 0) ? A0 : (p == 1) ? A1 : A2;
                src = Ap + (aRow0 + t + r) * 384 + koff;
            } else {
                const ushort* Bp = (p == 3) ? B0 : (p == 4) ? B1 : B2;
                src = Bp + (size_t)(col0 + r) * 1152 + t * 384 + koff;
            }
            gll16(src, dst0 + p * 4096 + sub * 512 + lane * 8);
        }
    };

    constexpr int PA[6] = {0, 0, 1, 1, 0, 2};
    constexpr int PB[6] = {0, 1, 0, 1, 2, 0};

    STAGE(0, 0, 0);
    __syncthreads();

    for (int s = 0; s < 36; ++s) {
        if (s < 35) {
            const int sn = s + 1;
            const int tn = (sn >= 24) ? 2 : (sn >= 12) ? 1 : 0;
            STAGE(tn, sn - tn * 12, sn & 1);
        }
        // ---- compute current stage from LDS
        const char* base = (const char*)smem + (s & 1) * 49152;
        bf16x8 ap[3][4], bp[3][4];
        #pragma unroll
        for (int p = 0; p < 3; ++p)
            #pragma unroll
            for (int i = 0; i < 4; ++i)
                ap[p][i] = *(const bf16x8*)(base + p * 8192 + i * 1024 + raddA);
        #pragma unroll
        for (int p = 0; p < 3; ++p)
            #pragma unroll
            for (int j = 0; j < 4; ++j)
                bp[p][j] = *(const bf16x8*)(base + 24576 + p * 8192 + j * 1024 + raddB);

        #pragma unroll
        for (int uu = 0; uu < 6; ++uu)
            #pragma unroll
            for (int i = 0; i < 4; ++i)
                #pragma unroll
                for (int j = 0; j < 4; ++j)
                    acc[i][j] = __builtin_amdgcn_mfma_f32_16x16x32_bf16(
                        ap[PA[uu]][i], bp[PB[uu]][j], acc[i][j], 0, 0, 0);

        __syncthreads();   // drains this wave's just-issued next-stage loads too
    }

    // ---- epilogue: +bias, relu, fp32 store
    float bj[4];
    #pragma unroll
    for (int j = 0; j < 4; ++j) bj[j] = bias[col0 + wc * 64 + j * 16 + lm];
    const int r4 = gk * 4;
    #pragma unroll
    for (int i = 0; i < 4; ++i) {
        #pragma unroll
        for (int q = 0; q < 4; ++q) {
            const size_t row = (size_t)row0 + wr * 64 + i * 16 + r4 + q;
            float* yr = Y + row * D_ + col0 + wc * 64 + lm;
            #pragma unroll
            for (int j = 0; j < 4; ++j)
                yr[j * 16] = fmaxf(acc[i][j][q] + bj[j], 0.f);
        }
    }
}

// ---------------------------------------------------------------------------
// LayerNorm + final linear (384 -> 1): writes log_pred[row].
// ---------------------------------------------------------------------------
__global__ __launch_bounds__(256)
void ln_linear_kernel(const float* __restrict__ in, const float* __restrict__ g,
                      const float* __restrict__ bta, const float* __restrict__ lw,
                      const float* __restrict__ lb, float* __restrict__ lp)
{
    const int gw   = (int)((blockIdx.x * blockDim.x + threadIdx.x) >> 6);
    const int lane = threadIdx.x & 63;
    if (gw >= NTOK) return;
    const float* row = in + (size_t)gw * D_;

    float v[6];
    float s = 0.f;
    #pragma unroll
    for (int j = 0; j < 3; ++j) {
        float2 t = *(const float2*)(row + ((j << 6) + lane) * 2);
        v[2 * j] = t.x; v[2 * j + 1] = t.y;
        s += t.x + t.y;
    }
    #pragma unroll
    for (int off = 32; off >= 1; off >>= 1) s += __shfl_xor(s, off);
    const float mean = s / 384.f;

    float q = 0.f;
    #pragma unroll
    for (int k = 0; k < 6; ++k) { float d = v[k] - mean; q += d * d; }
    #pragma unroll
    for (int off = 32; off >= 1; off >>= 1) q += __shfl_xor(q, off);
    const float rstd = 1.0f / sqrtf(q / 384.f + EPS_);

    float p = 0.f;
    #pragma unroll
    for (int j = 0; j < 3; ++j) {
        const int c = ((j << 6) + lane) * 2;
        p += ((v[2 * j]     - mean) * rstd * g[c]     + bta[c])     * lw[c];
        p += ((v[2 * j + 1] - mean) * rstd * g[c + 1] + bta[c + 1]) * lw[c + 1];
    }
    #pragma unroll
    for (int off = 32; off >= 1; off >>= 1) p += __shfl_xor(p, off);
    if (lane == 0) lp[gw] = p + lb[0];
}

// ---------------------------------------------------------------------------
__global__ __launch_bounds__(64)
void cumsum_kernel(const float* __restrict__ lp, int* __restrict__ cum)
{
    const int b    = blockIdx.x;
    const int lane = threadIdx.x;
    const int base = b * T_;

    int vals[16];
    int s = 0;
    #pragma unroll
    for (int j = 0; j < 16; ++j) {
        float e = expf(lp[base + lane * 16 + j]);
        int d = (int)rintf(e);
        vals[j] = d;
        s += d;
    }
    int incl = s;
    #pragma unroll
    for (int off = 1; off < 64; off <<= 1) {
        int n = __shfl_up(incl, off);
        if (lane >= off) incl += n;
    }
    int run = incl - s;
    #pragma unroll
    for (int j = 0; j < 16; ++j) {
        run += vals[j];
        cum[base + lane * 16 + j] = run;
    }
}

// ---------------------------------------------------------------------------
__global__ __launch_bounds__(256)
void gather_kernel(const float* __restrict__ X, const int* __restrict__ cum,
                   float* __restrict__ out)
{
    const int gw   = (int)((blockIdx.x * blockDim.x + threadIdx.x) >> 6);
    const int lane = threadIdx.x & 63;
    const int b    = gw / MAXF;
    const int fr   = gw % MAXF;

    const int* c = cum + b * T_;
    const int total = c[T_ - 1];

    int lo = 0, hi = T_;
    while (lo < hi) {
        int mid = (lo + hi) >> 1;
        if (c[mid] <= fr) lo = mid + 1; else hi = mid;
    }
    const int idx = min(lo, T_ - 1);
    const float mask = (fr < total) ? 1.0f : 0.0f;

    const float* src = X + ((size_t)b * T_ + idx) * D_;
    float* dst = out + (size_t)gw * D_;
    #pragma unroll
    for (int j = 0; j < 3; ++j) {
        const int c2 = ((j << 6) + lane) * 2;
        float2 t = *(const float2*)(src + c2);
        t.x *= mask; t.y *= mask;
        *(float2*)(dst + c2) = t;
    }
}

// ---------------------------------------------------------------------------
extern "C" void kernel_launch(void* const* d_in, const int* in_sizes, int n_in,
                              void* d_out, int out_size, void* d_ws, size_t ws_size,
                              hipStream_t stream)
{
    const float* x   = (const float*)d_in[0];
    const float* w1  = (const float*)d_in[1];
    const float* b1  = (const float*)d_in[2];
    const float* g1  = (const float*)d_in[3];
    const float* be1 = (const float*)d_in[4];
    const float* w2  = (const float*)d_in[5];
    const float* b2  = (const float*)d_in[6];
    const float* g2  = (const float*)d_in[7];
    const float* be2 = (const float*)d_in[8];
    const float* lw  = (const float*)d_in[9];
    const float* lb  = (const float*)d_in[10];

    float* out = (float*)d_out;

    // ---- arena layout in d_out (all floats; gather overwrites [0, 56623104)):
    const size_t SPf = (size_t)NPROW * 192;          // padded bf16 plane, in float slots
    ushort* X0 = (ushort*)(out);
    ushort* X1 = (ushort*)(out + SPf);
    ushort* X2 = (ushort*)(out + 2 * SPf);
    ushort* H0 = (ushort*)(out + 3 * SPf);
    ushort* H1 = (ushort*)(out + 4 * SPf);
    ushort* H2 = (ushort*)(out + 5 * SPf);
    float*  cvout = out + 6 * SPf;                   // conv fp32 out [NTOK,384]
    float*  wbase = cvout + (size_t)NTOK * D_;
    const size_t WPf = 384 * 576;                    // 221,184 float slots per bf16 w-plane
    ushort* W0 = (ushort*)(wbase);
    ushort* W1p = (ushort*)(wbase + WPf);
    ushort* W2p = (ushort*)(wbase + 2 * WPf);
    ushort* V0 = (ushort*)(wbase + 3 * WPf);
    ushort* V1 = (ushort*)(wbase + 4 * WPf);
    ushort* V2 = (ushort*)(wbase + 5 * WPf);
    float*  lp  = out + (size_t)B_ * MAXF * D_;      // real output #2
    int*    cum = (int*)d_ws;

    prep_kernel<<<XBLKS + 2 * WBLKS, 256, 0, stream>>>(
        x, X0, X1, X2, w1, W0, W1p, W2p, w2, V0, V1, V2);

    conv_mfma_kernel<<<768, 256, 0, stream>>>(X0, X1, X2, W0, W1p, W2p, b1, cvout);
    ln_split_kernel<<<(NPROW + 3) / 4, 256, 0, stream>>>(cvout, g1, be1, H0, H1, H2);
    conv_mfma_kernel<<<768, 256, 0, stream>>>(H0, H1, H2, V0, V1, V2, b2, cvout);
    ln_linear_kernel<<<NTOK / 4, 256, 0, stream>>>(cvout, g2, be2, lw, lb, lp);
    cumsum_kernel<<<B_, 64, 0, stream>>>(lp, cum);
    gather_kernel<<<(B_ * MAXF) / 4, 256, 0, stream>>>(x, cum, out);
}

// Round 4
// 539.809 us; speedup vs baseline: 3.3078x; 3.3078x over previous
//
#include <hip/hip_runtime.h>
#include <hip/hip_bf16.h>
#include <hip/hip_fp16.h>
#include <math.h>

#define B_    32
#define T_    1024
#define D_    384
#define MAXF  4608
#define NTOK  (B_ * T_)          // 32768
#define TPAD  1026               // per-batch padded token rows (zero row each side)
#define NPROW (B_ * TPAD)        // 32832 padded rows
#define EPS_  1e-5f

typedef _Float16 f16x8 __attribute__((ext_vector_type(8)));
typedef float    f32x4 __attribute__((ext_vector_type(4)));

// ---- fp32 -> fp16 x2 split (residual scaled by 2^12 to stay normal) -------
__device__ __forceinline__ void split2(float v, ushort& u0, ushort& u1) {
    _Float16 h0 = (_Float16)v;
    u0 = __builtin_bit_cast(ushort, h0);
    float r = (v - (float)h0) * 4096.f;
    _Float16 h1 = (_Float16)r;
    u1 = __builtin_bit_cast(ushort, h1);
}

__device__ __forceinline__ void gll16(const ushort* src, ushort* lds_dst) {
    __builtin_amdgcn_global_load_lds(
        (const __attribute__((address_space(1))) void*)src,
        (__attribute__((address_space(3))) void*)lds_dst, 16, 0, 0);
}

// ---------------------------------------------------------------------------
// prep kernel: x -> 2 padded fp16 planes; w1,w2 -> 2 transposed fp16 planes
// each (wT[n][kf], kf = t*384+c, row stride 1152).
// ---------------------------------------------------------------------------
#define XBLKS ((NPROW + 3) / 4)
#define WBLKS ((384 * 576 + 255) / 256)

__global__ __launch_bounds__(256)
void prep_kernel(const float* __restrict__ x,
                 ushort* __restrict__ X0, ushort* __restrict__ X1,
                 const float* __restrict__ w1,
                 ushort* __restrict__ W0, ushort* __restrict__ W1,
                 const float* __restrict__ w2,
                 ushort* __restrict__ V0, ushort* __restrict__ V1)
{
    int blk = blockIdx.x;
    if (blk < XBLKS) {
        const int row  = (int)((blk * 256 + threadIdx.x) >> 6);
        const int lane = threadIdx.x & 63;
        if (row >= NPROW) return;
        const int b = row / TPAD, tk = row % TPAD;

        uint* p0 = (uint*)X0 + (size_t)row * 192;
        uint* p1 = (uint*)X1 + (size_t)row * 192;

        if (tk == 0 || tk == TPAD - 1) {
            #pragma unroll
            for (int j = 0; j < 3; ++j) { p0[j * 64 + lane] = 0u; p1[j * 64 + lane] = 0u; }
            return;
        }
        const float* src = x + ((size_t)b * T_ + (tk - 1)) * D_;
        #pragma unroll
        for (int j = 0; j < 3; ++j) {
            float2 t = *(const float2*)(src + j * 128 + lane * 2);
            ushort a0, r0, a1, r1;
            split2(t.x, a0, r0);
            split2(t.y, a1, r1);
            p0[j * 64 + lane] = (uint)a0 | ((uint)a1 << 16);
            p1[j * 64 + lane] = (uint)r0 | ((uint)r1 << 16);
        }
        return;
    }
    blk -= XBLKS;
    const float* w;
    ushort *P0, *P1;
    if (blk < WBLKS) { w = w1; P0 = W0; P1 = W1; }
    else { blk -= WBLKS; w = w2; P0 = V0; P1 = V1; }

    const int p = blk * 256 + threadIdx.x;     // pair index
    if (p >= 384 * 576) return;
    const int n = p / 576, kp = p % 576;
    const int kf0 = kp * 2;
    float w0 = w[(size_t)kf0 * 384 + n];
    float w1v = w[(size_t)(kf0 + 1) * 384 + n];
    ushort a0, r0, a1, r1;
    split2(w0, a0, r0);
    split2(w1v, a1, r1);
    ((uint*)P0)[(size_t)n * 576 + kp] = (uint)a0 | ((uint)a1 << 16);
    ((uint*)P1)[(size_t)n * 576 + kp] = (uint)r0 | ((uint)r1 << 16);
}

// ---------------------------------------------------------------------------
// ln_split: LN(conv1_out) -> 2 fp16 padded planes (conv2's A operand).
// ---------------------------------------------------------------------------
__global__ __launch_bounds__(256)
void ln_split_kernel(const float* __restrict__ in, const float* __restrict__ g,
                     const float* __restrict__ bta,
                     ushort* __restrict__ P0, ushort* __restrict__ P1)
{
    const int row  = (int)((blockIdx.x * blockDim.x + threadIdx.x) >> 6);
    const int lane = threadIdx.x & 63;
    if (row >= NPROW) return;
    const int b = row / TPAD, tk = row % TPAD;

    uint* p0 = (uint*)P0 + (size_t)row * 192;
    uint* p1 = (uint*)P1 + (size_t)row * 192;

    if (tk == 0 || tk == TPAD - 1) {
        #pragma unroll
        for (int j = 0; j < 3; ++j) { p0[j * 64 + lane] = 0u; p1[j * 64 + lane] = 0u; }
        return;
    }
    const float* src = in + ((size_t)b * T_ + (tk - 1)) * D_;

    float v[6];
    float s = 0.f;
    #pragma unroll
    for (int j = 0; j < 3; ++j) {
        float2 t = *(const float2*)(src + j * 128 + lane * 2);
        v[2 * j] = t.x; v[2 * j + 1] = t.y;
        s += t.x + t.y;
    }
    #pragma unroll
    for (int off = 32; off >= 1; off >>= 1) s += __shfl_xor(s, off);
    const float mean = s / 384.f;
    float q = 0.f;
    #pragma unroll
    for (int k = 0; k < 6; ++k) { float d = v[k] - mean; q += d * d; }
    #pragma unroll
    for (int off = 32; off >= 1; off >>= 1) q += __shfl_xor(q, off);
    const float rstd = 1.0f / sqrtf(q / 384.f + EPS_);

    #pragma unroll
    for (int j = 0; j < 3; ++j) {
        const int c = j * 128 + lane * 2;
        float o0 = (v[2 * j]     - mean) * rstd * g[c]     + bta[c];
        float o1 = (v[2 * j + 1] - mean) * rstd * g[c + 1] + bta[c + 1];
        ushort a0, r0, a1, r1;
        split2(o0, a0, r0);
        split2(o1, a1, r1);
        p0[j * 64 + lane] = (uint)a0 | ((uint)a1 << 16);
        p1[j * 64 + lane] = (uint)r0 | ((uint)r1 << 16);
    }
}

// ---------------------------------------------------------------------------
// conv as fp16x2 MFMA GEMM, 3 combos (00 direct; 01+10 via scaled acc2).
// Per stage s (= tap*12 + kchunk): stage A0,A1,B0,B1 tiles (128r x 32k fp16,
// 8 KB each -> 32 KB), 2-barrier loop, 36 stages, 48 MFMA/wave/stage.
// Toeplitz: global source offset advances uniformly by s*32.
// LDS rows 64B, chunk swizzle f(R)=(R>>1)&3 -> 2-way (free) read conflicts.
// Tile 128x128, 4 waves (64x64), grid 768 XCD-swizzled.
// ---------------------------------------------------------------------------
__global__ __launch_bounds__(256, 3)
void conv_mfma_kernel(const ushort* __restrict__ A0, const ushort* __restrict__ A1,
                      const ushort* __restrict__ B0, const ushort* __restrict__ B1,
                      const float* __restrict__ bias, float* __restrict__ Y)
{
    __shared__ ushort smem[4 * 4096];   // 4 plane-tiles x 8 KB = 32 KB

    // XCD swizzle: 768 blocks, 96/XCD; 3 col-blocks of one row-block adjacent
    const int bid = blockIdx.x;
    const int u   = (bid & 7) * 96 + (bid >> 3);
    const int rb  = u / 3, cb = u - 3 * rb;
    const int row0 = rb * 128, col0 = cb * 128;
    const int b    = row0 >> 10;
    const int tk0  = row0 & (T_ - 1);

    const int tid  = threadIdx.x;
    const int wid  = tid >> 6;
    const int lane = tid & 63;
    const int wr   = wid >> 1, wc = wid & 1;

    // ---- staging: wave wid owns plane wid (A0,A1,B0,B1)
    const int r0l  = lane >> 2;                        // row within 16-row group
    const int clog = (lane & 3) ^ ((lane >> 3) & 3);   // source chunk for phys lane&3
    const ushort* P = (wid == 0) ? A0 : (wid == 1) ? A1 : (wid == 2) ? B0 : B1;
    const bool isA = (wid < 2);
    const size_t aRow0 = (size_t)(b * TPAD + tk0);

    uint aoff[8];
    #pragma unroll
    for (int sub = 0; sub < 8; ++sub) {
        const int r = sub * 16 + r0l;
        aoff[sub] = isA ? (uint)((aRow0 + r) * 384 + clog * 8)
                        : (uint)((size_t)(col0 + r) * 1152 + clog * 8);
    }
    ushort* dst0 = smem + wid * 4096 + lane * 8;

    // ---- fragment-read constants
    const int lm = lane & 15, gk = lane >> 4;
    const int swz   = ((gk ^ ((lm >> 1) & 3)) << 4);
    const int raddA = (wr * 64 + lm) * 64 + swz;   // + i*1024, plane A1 at +8192
    const int raddB = (wc * 64 + lm) * 64 + swz;   // + j*1024, planes at +16384/+24576

    f32x4 acc[4][4];
    #pragma unroll
    for (int i = 0; i < 4; ++i)
        #pragma unroll
        for (int j = 0; j < 4; ++j) { f32x4 z = {0.f, 0.f, 0.f, 0.f}; acc[i][j] = z; }

    const char* basec = (const char*)smem;

    for (int s = 0; s < 36; ++s) {
        // stage: 8 x 1KB wave-loads of this wave's plane
        #pragma unroll
        for (int sub = 0; sub < 8; ++sub)
            gll16(P + aoff[sub] + s * 32, dst0 + sub * 512);
        __syncthreads();                       // vmcnt drain + barrier

        f16x8 a0[4], a1[4];
        #pragma unroll
        for (int i = 0; i < 4; ++i) {
            a0[i] = *(const f16x8*)(basec +         i * 1024 + raddA);
            a1[i] = *(const f16x8*)(basec +  8192 + i * 1024 + raddA);
        }
        #pragma unroll
        for (int jh = 0; jh < 2; ++jh) {
            f16x8 b0[2], b1[2];
            #pragma unroll
            for (int j2 = 0; j2 < 2; ++j2) {
                b0[j2] = *(const f16x8*)(basec + 16384 + (jh * 2 + j2) * 1024 + raddB);
                b1[j2] = *(const f16x8*)(basec + 24576 + (jh * 2 + j2) * 1024 + raddB);
            }
            f32x4 t2[4][2];
            #pragma unroll
            for (int i = 0; i < 4; ++i)
                #pragma unroll
                for (int j2 = 0; j2 < 2; ++j2) { f32x4 z = {0.f,0.f,0.f,0.f}; t2[i][j2] = z; }
            #pragma unroll
            for (int i = 0; i < 4; ++i)
                #pragma unroll
                for (int j2 = 0; j2 < 2; ++j2) {
                    acc[i][jh*2+j2] = __builtin_amdgcn_mfma_f32_16x16x32_f16(
                        a0[i], b0[j2], acc[i][jh*2+j2], 0, 0, 0);
                    t2[i][j2] = __builtin_amdgcn_mfma_f32_16x16x32_f16(
                        a0[i], b1[j2], t2[i][j2], 0, 0, 0);
                    t2[i][j2] = __builtin_amdgcn_mfma_f32_16x16x32_f16(
                        a1[i], b0[j2], t2[i][j2], 0, 0, 0);
                }
            #pragma unroll
            for (int i = 0; i < 4; ++i)
                #pragma unroll
                for (int j2 = 0; j2 < 2; ++j2)
                    #pragma unroll
                    for (int q = 0; q < 4; ++q)
                        acc[i][jh*2+j2][q] = fmaf(t2[i][j2][q], 2.44140625e-4f,
                                                  acc[i][jh*2+j2][q]);
        }
        __syncthreads();                       // reads done before next overwrite
    }

    // ---- epilogue: +bias, relu, fp32 store
    float bj[4];
    #pragma unroll
    for (int j = 0; j < 4; ++j) bj[j] = bias[col0 + wc * 64 + j * 16 + lm];
    const int r4 = gk * 4;
    #pragma unroll
    for (int i = 0; i < 4; ++i) {
        #pragma unroll
        for (int q = 0; q < 4; ++q) {
            const size_t row = (size_t)row0 + wr * 64 + i * 16 + r4 + q;
            float* yr = Y + row * D_ + col0 + wc * 64 + lm;
            #pragma unroll
            for (int j = 0; j < 4; ++j)
                yr[j * 16] = fmaxf(acc[i][j][q] + bj[j], 0.f);
        }
    }
}

// ---------------------------------------------------------------------------
// LayerNorm + final linear (384 -> 1): writes log_pred[row].
// ---------------------------------------------------------------------------
__global__ __launch_bounds__(256)
void ln_linear_kernel(const float* __restrict__ in, const float* __restrict__ g,
                      const float* __restrict__ bta, const float* __restrict__ lw,
                      const float* __restrict__ lb, float* __restrict__ lp)
{
    const int gw   = (int)((blockIdx.x * blockDim.x + threadIdx.x) >> 6);
    const int lane = threadIdx.x & 63;
    if (gw >= NTOK) return;
    const float* row = in + (size_t)gw * D_;

    float v[6];
    float s = 0.f;
    #pragma unroll
    for (int j = 0; j < 3; ++j) {
        float2 t = *(const float2*)(row + ((j << 6) + lane) * 2);
        v[2 * j] = t.x; v[2 * j + 1] = t.y;
        s += t.x + t.y;
    }
    #pragma unroll
    for (int off = 32; off >= 1; off >>= 1) s += __shfl_xor(s, off);
    const float mean = s / 384.f;

    float q = 0.f;
    #pragma unroll
    for (int k = 0; k < 6; ++k) { float d = v[k] - mean; q += d * d; }
    #pragma unroll
    for (int off = 32; off >= 1; off >>= 1) q += __shfl_xor(q, off);
    const float rstd = 1.0f / sqrtf(q / 384.f + EPS_);

    float p = 0.f;
    #pragma unroll
    for (int j = 0; j < 3; ++j) {
        const int c = ((j << 6) + lane) * 2;
        p += ((v[2 * j]     - mean) * rstd * g[c]     + bta[c])     * lw[c];
        p += ((v[2 * j + 1] - mean) * rstd * g[c + 1] + bta[c + 1]) * lw[c + 1];
    }
    #pragma unroll
    for (int off = 32; off >= 1; off >>= 1) p += __shfl_xor(p, off);
    if (lane == 0) lp[gw] = p + lb[0];
}

// ---------------------------------------------------------------------------
__global__ __launch_bounds__(64)
void cumsum_kernel(const float* __restrict__ lp, int* __restrict__ cum)
{
    const int b    = blockIdx.x;
    const int lane = threadIdx.x;
    const int base = b * T_;

    int vals[16];
    int s = 0;
    #pragma unroll
    for (int j = 0; j < 16; ++j) {
        float e = expf(lp[base + lane * 16 + j]);
        int d = (int)rintf(e);
        vals[j] = d;
        s += d;
    }
    int incl = s;
    #pragma unroll
    for (int off = 1; off < 64; off <<= 1) {
        int n = __shfl_up(incl, off);
        if (lane >= off) incl += n;
    }
    int run = incl - s;
    #pragma unroll
    for (int j = 0; j < 16; ++j) {
        run += vals[j];
        cum[base + lane * 16 + j] = run;
    }
}

// ---------------------------------------------------------------------------
__global__ __launch_bounds__(256)
void gather_kernel(const float* __restrict__ X, const int* __restrict__ cum,
                   float* __restrict__ out)
{
    const int gw   = (int)((blockIdx.x * blockDim.x + threadIdx.x) >> 6);
    const int lane = threadIdx.x & 63;
    const int b    = gw / MAXF;
    const int fr   = gw % MAXF;

    const int* c = cum + b * T_;
    const int total = c[T_ - 1];

    int lo = 0, hi = T_;
    while (lo < hi) {
        int mid = (lo + hi) >> 1;
        if (c[mid] <= fr) lo = mid + 1; else hi = mid;
    }
    const int idx = min(lo, T_ - 1);
    const float mask = (fr < total) ? 1.0f : 0.0f;

    const float* src = X + ((size_t)b * T_ + idx) * D_;
    float* dst = out + (size_t)gw * D_;
    #pragma unroll
    for (int j = 0; j < 3; ++j) {
        const int c2 = ((j << 6) + lane) * 2;
        float2 t = *(const float2*)(src + c2);
        t.x *= mask; t.y *= mask;
        *(float2*)(dst + c2) = t;
    }
}

// ---------------------------------------------------------------------------
extern "C" void kernel_launch(void* const* d_in, const int* in_sizes, int n_in,
                              void* d_out, int out_size, void* d_ws, size_t ws_size,
                              hipStream_t stream)
{
    const float* x   = (const float*)d_in[0];
    const float* w1  = (const float*)d_in[1];
    const float* b1  = (const float*)d_in[2];
    const float* g1  = (const float*)d_in[3];
    const float* be1 = (const float*)d_in[4];
    const float* w2  = (const float*)d_in[5];
    const float* b2  = (const float*)d_in[6];
    const float* g2  = (const float*)d_in[7];
    const float* be2 = (const float*)d_in[8];
    const float* lw  = (const float*)d_in[9];
    const float* lb  = (const float*)d_in[10];

    float* out = (float*)d_out;

    // ---- arena in d_out (gather overwrites [0, 56623104) at the end):
    const size_t SPf = (size_t)NPROW * 192;          // fp16 plane, float slots
    ushort* X0 = (ushort*)(out);
    ushort* X1 = (ushort*)(out + SPf);
    ushort* H0 = (ushort*)(out + 2 * SPf);
    ushort* H1 = (ushort*)(out + 3 * SPf);
    float*  cvout = out + 4 * SPf;                   // conv fp32 out [NTOK,384]
    float*  wbase = cvout + (size_t)NTOK * D_;
    const size_t WPf = 384 * 576;                    // float slots per fp16 w-plane
    ushort* W0 = (ushort*)(wbase);
    ushort* W1p = (ushort*)(wbase + WPf);
    ushort* V0 = (ushort*)(wbase + 2 * WPf);
    ushort* V1 = (ushort*)(wbase + 3 * WPf);
    float*  lp  = out + (size_t)B_ * MAXF * D_;      // real output #2
    int*    cum = (int*)d_ws;

    prep_kernel<<<XBLKS + 2 * WBLKS, 256, 0, stream>>>(
        x, X0, X1, w1, W0, W1p, w2, V0, V1);

    conv_mfma_kernel<<<768, 256, 0, stream>>>(X0, X1, W0, W1p, b1, cvout);
    ln_split_kernel<<<(NPROW + 3) / 4, 256, 0, stream>>>(cvout, g1, be1, H0, H1);
    conv_mfma_kernel<<<768, 256, 0, stream>>>(H0, H1, V0, V1, b2, cvout);
    ln_linear_kernel<<<NTOK / 4, 256, 0, stream>>>(cvout, g2, be2, lw, lb, lp);
    cumsum_kernel<<<B_, 64, 0, stream>>>(lp, cum);
    gather_kernel<<<(B_ * MAXF) / 4, 256, 0, stream>>>(x, cum, out);
}